// Round 15
// baseline (178.004 us; speedup 1.0000x reference)
//
#include <hip/hip_runtime.h>
#include <hip/hip_bf16.h>
#include <stdint.h>

// Problem constants
#define BATCH 2
#define TT 2048
#define DM 768
#define RR 4
#define M_TOK 4096          // B*T tokens
#define NFEAT 6144          // D*R*2
#define NCH 6144            // B*D*R channels
#define CHUNK 64            // scan chunk length
#define NCHUNK 32           // T / CHUNK

typedef __attribute__((ext_vector_type(8))) short short8;
typedef __attribute__((ext_vector_type(4))) float float4v;

// ---------- helpers ----------
__device__ inline float bf2f(uint32_t bits16) {
    union { uint32_t u; float f; } x; x.u = bits16 << 16; return x.f;
}

typedef const __attribute__((address_space(1))) void* gptr_t;
typedef __attribute__((address_space(3))) void* lptr_t;

__device__ inline void async_ld16(const void* g, void* l) {
    __builtin_amdgcn_global_load_lds((gptr_t)(uintptr_t)g, (lptr_t)(uintptr_t)l,
                                     16, 0, 0);
}

__device__ inline uint2 pack4bf(float a, float b, float c, float d) {
    union { __hip_bfloat16 h[4]; uint2 u; } o;
    o.h[0] = __float2bfloat16(a); o.h[1] = __float2bfloat16(b);
    o.h[2] = __float2bfloat16(c); o.h[3] = __float2bfloat16(d);
    return o.u;
}

__device__ inline float2 cmul(float2 a, float2 b) {
    return make_float2(a.x * b.x - a.y * b.y, a.x * b.y + a.y * b.x);
}
__device__ inline float2 cmad(float2 a, float2 b, float2 c) {
    // a*b + c
    return make_float2(a.x * b.x - a.y * b.y + c.x,
                       a.x * b.y + a.y * b.x + c.y);
}
__device__ inline float2 csq(float2 a) {
    return make_float2(a.x * a.x - a.y * a.y, 2.f * a.x * a.y);
}

// ---------- complex recurrence step: s = a*s + b*u ----------
__device__ inline void cstep(float& sr, float& si, float2 a, float2 bb,
                             uint32_t uw) {
    float ur = bf2f(uw & 0xffffu), ui = bf2f(uw >> 16);
    float tr = bb.x * ur - bb.y * ui;
    float ti = bb.x * ui + bb.y * ur;
    float nr = a.x * sr - a.y * si + tr;
    float ni = a.x * si + a.y * sr + ti;
    sr = nr; si = ni;
}

// ---------- fused prep + rmsnorm (R7-exact: block-per-token) ----------
__global__ __launch_bounds__(256) void prep_rms(
    const float* __restrict__ x, const float* __restrict__ w,
    const float* __restrict__ W_in, const float* __restrict__ W_out,
    const float* __restrict__ ap, const float* __restrict__ bp,
    const float* __restrict__ cp,
    __hip_bfloat16* __restrict__ xn,
    __hip_bfloat16* __restrict__ Win_bf, __hip_bfloat16* __restrict__ Wout_bf,
    float2* __restrict__ ac, float2* __restrict__ bc,
    float2* __restrict__ cc, float2* __restrict__ aL) {
    int bid = blockIdx.x;
    int tid = threadIdx.x;
    if (bid < M_TOK) {
        // ---- RMSNorm for token `bid` ----
        __shared__ float wsum[3];
        float4 v = make_float4(0.f, 0.f, 0.f, 0.f);
        if (tid < 192) v = ((const float4*)(x + (size_t)bid * DM))[tid];
        float ss = v.x * v.x + v.y * v.y + v.z * v.z + v.w * v.w;
        #pragma unroll
        for (int o = 1; o < 64; o <<= 1) ss += __shfl_xor(ss, o);
        if (tid < 192 && (tid & 63) == 0) wsum[tid >> 6] = ss;
        __syncthreads();
        if (tid < 192) {
            float tot = wsum[0] + wsum[1] + wsum[2];
            float scale = rsqrtf(tot * (1.f / DM) + 1e-6f);
            float4 wv = ((const float4*)w)[tid];
            ((uint2*)(xn + (size_t)bid * DM))[tid] =
                pack4bf(v.x * scale * wv.x, v.y * scale * wv.y,
                        v.z * scale * wv.z, v.w * scale * wv.w);
        }
        return;
    }
    const int N1 = NFEAT * DM / 4;   // float4 count
    const int N2 = DM * DM / 4;
    int i = (bid - M_TOK) * 256 + tid;
    if (i < N1) {
        float4 v = ((const float4*)W_in)[i];
        ((uint2*)Win_bf)[i] = pack4bf(v.x, v.y, v.z, v.w);
    } else if (i < N1 + N2) {
        int k = i - N1;
        float4 v = ((const float4*)W_out)[k];
        ((uint2*)Wout_bf)[k] = pack4bf(v.x, v.y, v.z, v.w);
    }
    if (i < DM * RR) {
        float ar = tanhf(ap[2 * i])     * 0.97f;
        float ai = tanhf(ap[2 * i + 1]) * 0.97f;
        ac[i] = make_float2(ar, ai);
        bc[i] = make_float2(tanhf(bp[2 * i]), tanhf(bp[2 * i + 1]));
        cc[i] = make_float2(tanhf(cp[2 * i]), tanhf(cp[2 * i + 1]));
        float xr = ar, xi = ai;   // a^64 via 6 squarings
        #pragma unroll
        for (int k = 0; k < 6; ++k) {
            float nr = xr * xr - xi * xi;
            float ni = 2.f * xr * xi;
            xr = nr; xi = ni;
        }
        aL[i] = make_float2(xr, xi);
    }
}

// ---------- gemm_in: R9 config + T1 XCD-aware block swizzle ----------
// Family bracket: R0=50.4; R8=47.5; R9/R11/R13=45.0-46.1 (BEST, at the
// 2-barrier family's LDS-port ceiling: 34.5us reads + 11.8us staging ~ 46.3);
// R10 128x256=51.2; R12 BK=32=59.6; R14 fused-scan=73.4 (write amplification
// + serial tail — fusion closed). This round adds the one untested technique:
// T1 XCD swizzle (grid 1536%8==0 -> bijective). Each XCD gets 4 contiguous
// by-rows: A-panels (4x192KB) L2-resident per XCD despite the 49MB u
// write-stream churning L3. Expected small or null (24% HBM); zero risk.
__global__ __launch_bounds__(512, 4) void gemm_in(
    const __hip_bfloat16* __restrict__ A, const __hip_bfloat16* __restrict__ B,
    __hip_bfloat16* __restrict__ C, int K) {
    constexpr int BM = 128, BN = 128, BK = 64;
    constexpr int CPR = BK / 8;           // 8 chunks per row
    constexpr int ldc = NFEAT;
    __shared__ __attribute__((aligned(16))) __hip_bfloat16
        lds2[2][BM * BK + BN * BK];
    const int tid  = threadIdx.x;
    const int lane = tid & 63;
    const int wave = tid >> 6;            // 0..7
    const int quad = lane >> 4;
    const int l15  = lane & 15;
    const int wm = (wave >> 2) * 64;      // 2 wave-rows
    const int wn = (wave & 3) * 32;       // 4 wave-cols
    // T1: XCD-aware swizzle of the linear workgroup id (1536 = 8 * 192)
    const int lin = blockIdx.y * 48 + blockIdx.x;
    const int swz = (lin & 7) * 192 + (lin >> 3);
    const int m0 = (swz / 48) * BM;
    const int n0 = (swz % 48) * BN;

    float4v acc[4][2] = {};

    auto stage = [&](int bi, int t) {
        __hip_bfloat16* sA = lds2[bi];
        __hip_bfloat16* sB = lds2[bi] + BM * BK;
        const int k0 = t * BK;
        #pragma unroll
        for (int it = 0; it < BM * CPR / 512; ++it) {   // 2
            int p = it * 512 + tid;
            int row = p >> 3;
            int cg = (p & 7) ^ (row & 7);
            async_ld16(A + (size_t)(m0 + row) * K + k0 + cg * 8, sA + p * 8);
        }
        #pragma unroll
        for (int it = 0; it < BN * CPR / 512; ++it) {   // 2
            int p = it * 512 + tid;
            int row = p >> 3;
            int cg = (p & 7) ^ (row & 7);
            async_ld16(B + (size_t)(n0 + row) * K + k0 + cg * 8, sB + p * 8);
        }
    };

    const int nt = K / BK;          // 12
    stage(0, 0);
    for (int t = 0; t < nt; ++t) {
        const int cur = t & 1;
        if (t + 1 < nt) {
            stage(cur ^ 1, t + 1);
            asm volatile("s_waitcnt vmcnt(4)" ::: "memory");
        } else {
            asm volatile("s_waitcnt vmcnt(0)" ::: "memory");
        }
        asm volatile("s_barrier" ::: "memory");
        const __hip_bfloat16* lA = lds2[cur];
        const __hip_bfloat16* lB = lds2[cur] + BM * BK;
        #pragma unroll
        for (int s = 0; s < BK / 32; ++s) {
            short8 af[4], bfr[2];
            #pragma unroll
            for (int i = 0; i < 4; ++i) {
                int r = wm + i * 16 + l15;
                int c = (s * 4 + quad) ^ (r & 7);
                af[i] = *(const short8*)(lA + r * BK + c * 8);
            }
            #pragma unroll
            for (int j = 0; j < 2; ++j) {
                int r = wn + j * 16 + l15;
                int c = (s * 4 + quad) ^ (r & 7);
                bfr[j] = *(const short8*)(lB + r * BK + c * 8);
            }
            #pragma unroll
            for (int i = 0; i < 4; ++i)
                #pragma unroll
                for (int j = 0; j < 2; ++j)
                    acc[i][j] = __builtin_amdgcn_mfma_f32_16x16x32_bf16(
                        af[i], bfr[j], acc[i][j], 0, 0, 0);
        }
        asm volatile("s_waitcnt lgkmcnt(0)" ::: "memory");
        asm volatile("s_barrier" ::: "memory");
    }
    // epilogue: C/D layout col = lane&15, row = quad*4 + reg (m89-verified)
    #pragma unroll
    for (int i = 0; i < 4; ++i)
        #pragma unroll
        for (int j = 0; j < 2; ++j)
            #pragma unroll
            for (int rg = 0; rg < 4; ++rg) {
                int row = m0 + wm + i * 16 + quad * 4 + rg;
                int col = n0 + wn + j * 16 + l15;
                C[(size_t)row * ldc + col] = __float2bfloat16(acc[i][j][rg]);
            }
}

// ---------- gemm_out v2: counted-vmcnt dbuf at 64x64 (R13, passing) -------
__global__ __launch_bounds__(256, 4) void gemm_out(
    const __hip_bfloat16* __restrict__ A, const __hip_bfloat16* __restrict__ B,
    float* __restrict__ C, int K) {
    constexpr int BM = 64, BN = 64, BK = 64;
    constexpr int CPR = BK / 8;           // 8
    constexpr int ldc = DM;
    __shared__ __attribute__((aligned(16))) __hip_bfloat16
        lds2[2][(BM + BN) * BK];
    const int tid  = threadIdx.x;
    const int lane = tid & 63;
    const int wave = tid >> 6;            // 0..3
    const int quad = lane >> 4;
    const int l15  = lane & 15;
    const int wm = (wave >> 1) * 32;      // 2 wave-rows
    const int wn = (wave & 1) * 32;       // 2 wave-cols
    const int m0 = blockIdx.y * BM;
    const int n0 = blockIdx.x * BN;

    float4v acc[2][2] = {};

    auto stage = [&](int bi, int t) {
        __hip_bfloat16* sA = lds2[bi];
        __hip_bfloat16* sB = lds2[bi] + BM * BK;
        const int k0 = t * BK;
        #pragma unroll
        for (int it = 0; it < BM * CPR / 256; ++it) {   // 2
            int p = it * 256 + tid;
            int row = p >> 3;
            int cg = (p & 7) ^ (row & 7);
            async_ld16(A + (size_t)(m0 + row) * K + k0 + cg * 8, sA + p * 8);
        }
        #pragma unroll
        for (int it = 0; it < BN * CPR / 256; ++it) {   // 2
            int p = it * 256 + tid;
            int row = p >> 3;
            int cg = (p & 7) ^ (row & 7);
            async_ld16(B + (size_t)(n0 + row) * K + k0 + cg * 8, sB + p * 8);
        }
    };

    const int nt = K / BK;          // 12
    stage(0, 0);
    for (int t = 0; t < nt; ++t) {
        const int cur = t & 1;
        if (t + 1 < nt) {
            stage(cur ^ 1, t + 1);
            asm volatile("s_waitcnt vmcnt(4)" ::: "memory");
        } else {
            asm volatile("s_waitcnt vmcnt(0)" ::: "memory");
        }
        asm volatile("s_barrier" ::: "memory");
        const __hip_bfloat16* lA = lds2[cur];
        const __hip_bfloat16* lB = lds2[cur] + BM * BK;
        #pragma unroll
        for (int s = 0; s < BK / 32; ++s) {
            short8 af[2], bfr[2];
            #pragma unroll
            for (int i = 0; i < 2; ++i) {
                int r = wm + i * 16 + l15;
                int c = (s * 4 + quad) ^ (r & 7);
                af[i] = *(const short8*)(lA + r * BK + c * 8);
            }
            #pragma unroll
            for (int j = 0; j < 2; ++j) {
                int r = wn + j * 16 + l15;
                int c = (s * 4 + quad) ^ (r & 7);
                bfr[j] = *(const short8*)(lB + r * BK + c * 8);
            }
            #pragma unroll
            for (int i = 0; i < 2; ++i)
                #pragma unroll
                for (int j = 0; j < 2; ++j)
                    acc[i][j] = __builtin_amdgcn_mfma_f32_16x16x32_bf16(
                        af[i], bfr[j], acc[i][j], 0, 0, 0);
        }
        asm volatile("s_waitcnt lgkmcnt(0)" ::: "memory");
        asm volatile("s_barrier" ::: "memory");
    }
    // epilogue: C/D layout col = lane&15, row = quad*4 + reg (m89-verified)
    #pragma unroll
    for (int i = 0; i < 2; ++i)
        #pragma unroll
        for (int j = 0; j < 2; ++j)
            #pragma unroll
            for (int rg = 0; rg < 4; ++rg) {
                int row = m0 + wm + i * 16 + quad * 4 + rg;
                int col = n0 + wn + j * 16 + l15;
                C[(size_t)row * ldc + col] = acc[i][j][rg];
            }
}

// ---------- scan_local2: standalone two-level chunk scan (R4, passing) ----
__global__ __launch_bounds__(256) void scan_local2(
    const uint4* __restrict__ u4,              // [token*768 + d] (4 ranks)
    const float2* __restrict__ ac, const float2* __restrict__ bc,
    const float2* __restrict__ cc,
    __hip_bfloat16* __restrict__ y_local,      // [M_TOK][DM] bf16
    float2* __restrict__ chunkEnd) {           // [NCHUNK][NCH]
    __shared__ float2 se[1024];                // 256 threads x 4 ranks
    const int tid   = threadIdx.x;
    const int d_loc = tid & 31;
    const int s8    = tid >> 5;
    const int bd    = blockIdx.x;              // 0..47
    const int b     = bd >= 24;
    const int dg    = bd - b * 24;
    const int d_g   = dg * 32 + d_loc;
    const int cb    = d_g * RR;
    const int j     = blockIdx.y;

    float2 a0 = ac[cb], a1 = ac[cb + 1], a2 = ac[cb + 2], a3 = ac[cb + 3];
    float2 b0 = bc[cb], b1 = bc[cb + 1], b2 = bc[cb + 2], b3 = bc[cb + 3];
    float2 c0 = cc[cb], c1 = cc[cb + 1], c2 = cc[cb + 2], c3 = cc[cb + 3];

    const int token0 = b * TT + j * CHUNK + s8 * 8;
    const size_t base = (size_t)token0 * DM + d_g;   // uint4 stride DM/token

    // Phase A: issue all 8 loads, then 8-token sub-scan (zero init)
    uint4 uw[8];
    #pragma unroll
    for (int i = 0; i < 8; ++i) uw[i] = u4[base + (size_t)i * DM];
    float s0r = 0, s0i = 0, s1r = 0, s1i = 0;
    float s2r = 0, s2i = 0, s3r = 0, s3i = 0;
    float yloc[8];
    #pragma unroll
    for (int i = 0; i < 8; ++i) {
        cstep(s0r, s0i, a0, b0, uw[i].x);
        cstep(s1r, s1i, a1, b1, uw[i].y);
        cstep(s2r, s2i, a2, b2, uw[i].z);
        cstep(s3r, s3i, a3, b3, uw[i].w);
        yloc[i] = c0.x * s0r - c0.y * s0i + c1.x * s1r - c1.y * s1i
                + c2.x * s2r - c2.y * s2i + c3.x * s3r - c3.y * s3i;
    }
    se[tid * 4]     = make_float2(s0r, s0i);
    se[tid * 4 + 1] = make_float2(s1r, s1i);
    se[tid * 4 + 2] = make_float2(s2r, s2i);
    se[tid * 4 + 3] = make_float2(s3r, s3i);
    __syncthreads();

    // Phase B: fold preceding sub-ends with aE = a^8
    float2 aE0 = csq(csq(csq(a0))), aE1 = csq(csq(csq(a1)));
    float2 aE2 = csq(csq(csq(a2))), aE3 = csq(csq(csq(a3)));
    float2 C0 = make_float2(0, 0), C1 = C0, C2 = C0, C3 = C0;
    for (int k = 0; k < s8; ++k) {
        int kb = (k * 32 + d_loc) * 4;
        C0 = cmad(C0, aE0, se[kb]);
        C1 = cmad(C1, aE1, se[kb + 1]);
        C2 = cmad(C2, aE2, se[kb + 2]);
        C3 = cmad(C3, aE3, se[kb + 3]);
    }
    // chunkEnd from slice 7: end = C*aE + own sub-end (still in regs)
    if (s8 == 7) {
        size_t eb = (size_t)j * NCH + b * (DM * RR) + cb;
        chunkEnd[eb]     = cmad(C0, aE0, make_float2(s0r, s0i));
        chunkEnd[eb + 1] = cmad(C1, aE1, make_float2(s1r, s1i));
        chunkEnd[eb + 2] = cmad(C2, aE2, make_float2(s2r, s2i));
        chunkEnd[eb + 3] = cmad(C3, aE3, make_float2(s3r, s3i));
    }
    // correction: y_i += Re(c * a^(i+1) * C), then store bf16
    float2 q0 = cmul(cmul(c0, C0), a0);
    float2 q1 = cmul(cmul(c1, C1), a1);
    float2 q2 = cmul(cmul(c2, C2), a2);
    float2 q3 = cmul(cmul(c3, C3), a3);
    #pragma unroll
    for (int i = 0; i < 8; ++i) {
        float yv = yloc[i] + q0.x + q1.x + q2.x + q3.x;
        y_local[base + (size_t)i * DM] = __float2bfloat16(yv);
        q0 = cmul(q0, a0); q1 = cmul(q1, a1);
        q2 = cmul(q2, a2); q3 = cmul(q3, a3);
    }
}

// ---------- carry_scan: per-channel sequential fold, IN PLACE (R7) --------
__global__ __launch_bounds__(256) void carry_scan(
    float2* __restrict__ chunkEnd,             // [NCHUNK][NCH], in/out
    const float2* __restrict__ aLp) {          // [DM*RR] = a^64
    int ch = blockIdx.x * 256 + threadIdx.x;   // 0..NCH-1 = b*(DM*RR)+d*RR+r
    int dr = (ch >= DM * RR) ? ch - DM * RR : ch;
    float2 aL = aLp[dr];
    float2 K = make_float2(0.f, 0.f);
    for (int j = 0; j < NCHUNK; ++j) {
        size_t idx = (size_t)j * NCH + ch;
        float2 e = chunkEnd[idx];
        chunkEnd[idx] = K;
        K = cmad(K, aL, e);
    }
}

// ---------- scan_fix: foldless carry correction, IN PLACE (R7) ------------
__global__ __launch_bounds__(256) void scan_fix(
    __hip_bfloat16* __restrict__ y_local,      // in/out [M_TOK][DM]
    const float2* __restrict__ ac, const float2* __restrict__ cc,
    const float2* __restrict__ carry) {        // [NCHUNK][NCH] (=chunkEnd)
    const int tid   = threadIdx.x;
    const int d_loc = tid & 31;
    const int s8    = tid >> 5;
    const int bd    = blockIdx.x;              // 0..47
    const int b     = bd >= 24;
    const int dg    = bd - b * 24;
    const int d_g   = dg * 32 + d_loc;
    const int cb    = d_g * RR;
    const int j     = blockIdx.y;
    const size_t kb = (size_t)j * NCH + b * (DM * RR) + cb;

    float2 a0 = ac[cb], a1 = ac[cb + 1], a2 = ac[cb + 2], a3 = ac[cb + 3];
    float2 c0 = cc[cb], c1 = cc[cb + 1], c2 = cc[cb + 2], c3 = cc[cb + 3];
    float2 K0 = carry[kb],     K1 = carry[kb + 1];
    float2 K2 = carry[kb + 2], K3 = carry[kb + 3];

    // q = c * K * a^(8*s8 + 1)
    float2 aE0 = csq(csq(csq(a0))), aE1 = csq(csq(csq(a1)));
    float2 aE2 = csq(csq(csq(a2))), aE3 = csq(csq(csq(a3)));
    float2 q0 = cmul(cmul(c0, K0), a0);
    float2 q1 = cmul(cmul(c1, K1), a1);
    float2 q2 = cmul(cmul(c2, K2), a2);
    float2 q3 = cmul(cmul(c3, K3), a3);
    for (int t = 0; t < s8; ++t) {
        q0 = cmul(q0, aE0); q1 = cmul(q1, aE1);
        q2 = cmul(q2, aE2); q3 = cmul(q3, aE3);
    }
    const int token0 = b * TT + j * CHUNK + s8 * 8;
    const size_t base = (size_t)token0 * DM + d_g;
    #pragma unroll
    for (int i = 0; i < 8; ++i) {
        size_t idx = base + (size_t)i * DM;
        float yv = bf2f(((const uint16_t*)y_local)[idx])
                 + q0.x + q1.x + q2.x + q3.x;
        y_local[idx] = __float2bfloat16(yv);
        q0 = cmul(q0, a0); q1 = cmul(q1, a1);
        q2 = cmul(q2, a2); q3 = cmul(q3, a3);
    }
}

// ---------- launch ----------
extern "C" void kernel_launch(void* const* d_in, const int* in_sizes, int n_in,
                              void* d_out, int out_size, void* d_ws,
                              size_t ws_size, hipStream_t stream) {
    const float* x      = (const float*)d_in[0];
    const float* norm_w = (const float*)d_in[1];
    const float* W_in   = (const float*)d_in[2];
    const float* W_out  = (const float*)d_in[3];
    const float* a_p    = (const float*)d_in[4];
    const float* b_p    = (const float*)d_in[5];
    const float* c_p    = (const float*)d_in[6];
    float* out = (float*)d_out;

    char* ws = (char*)d_ws;
    size_t off = 0;
    auto alloc = [&](size_t bytes) {
        void* p = ws + off;
        off += (bytes + 255) & ~(size_t)255;
        return p;
    };
    __hip_bfloat16* Win_bf  = (__hip_bfloat16*)alloc((size_t)NFEAT * DM * 2);
    __hip_bfloat16* Wout_bf = (__hip_bfloat16*)alloc((size_t)DM * DM * 2);
    __hip_bfloat16* xn      = (__hip_bfloat16*)alloc((size_t)M_TOK * DM * 2);
    __hip_bfloat16* u       = (__hip_bfloat16*)alloc((size_t)M_TOK * NFEAT * 2);
    __hip_bfloat16* y_local = (__hip_bfloat16*)alloc((size_t)M_TOK * DM * 2);
    float2* ac = (float2*)alloc((size_t)DM * RR * 8);
    float2* bc = (float2*)alloc((size_t)DM * RR * 8);
    float2* cc = (float2*)alloc((size_t)DM * RR * 8);
    float2* aL = (float2*)alloc((size_t)DM * RR * 8);
    float2* chunkEnd = (float2*)alloc((size_t)NCHUNK * NCH * 8);

    // 1. fused prep (weight casts + coeffs) + RMSNorm
    {
        int cast_blocks = ((NFEAT * DM + DM * DM) / 4 + 255) / 256;
        prep_rms<<<M_TOK + cast_blocks, 256, 0, stream>>>(
            x, norm_w, W_in, W_out, a_p, b_p, c_p,
            xn, Win_bf, Wout_bf, ac, bc, cc, aL);
    }
    // 2. in_proj GEMM: u = xn @ W_in^T  (R9 config + XCD swizzle)
    gemm_in<<<dim3(NFEAT / 128, M_TOK / 128), 512, 0, stream>>>(
        xn, Win_bf, u, DM);
    // 3. two-level chunk scan: u -> y_local + chunkEnd
    scan_local2<<<dim3(48, NCHUNK), 256, 0, stream>>>(
        (const uint4*)u, ac, bc, cc, y_local, chunkEnd);
    // 4. per-channel carry fold (in place: chunkEnd -> carry-entering-chunk)
    carry_scan<<<NCH / 256, 256, 0, stream>>>(chunkEnd, aL);
    // 5. foldless correction, in place on y_local
    scan_fix<<<dim3(48, NCHUNK), 256, 0, stream>>>(
        y_local, ac, cc, chunkEnd);
    // 6. out_proj GEMM (counted-vmcnt dbuf, 64^2, BK=64)
    gemm_out<<<dim3(DM / 64, M_TOK / 64), 256, 0, stream>>>(
        y_local, Wout_bf, out, DM);
}

// Round 16
// 167.931 us; speedup vs baseline: 1.0600x; 1.0600x over previous
//
#include <hip/hip_runtime.h>
#include <hip/hip_bf16.h>
#include <stdint.h>

// Problem constants
#define BATCH 2
#define TT 2048
#define DM 768
#define RR 4
#define M_TOK 4096          // B*T tokens
#define NFEAT 6144          // D*R*2
#define NCH 6144            // B*D*R channels
#define CHUNK 64            // scan chunk length
#define NCHUNK 32           // T / CHUNK

typedef __attribute__((ext_vector_type(8))) short short8;
typedef __attribute__((ext_vector_type(4))) float float4v;

// ---------- helpers ----------
__device__ inline float bf2f(uint32_t bits16) {
    union { uint32_t u; float f; } x; x.u = bits16 << 16; return x.f;
}

typedef const __attribute__((address_space(1))) void* gptr_t;
typedef __attribute__((address_space(3))) void* lptr_t;

__device__ inline void async_ld16(const void* g, void* l) {
    __builtin_amdgcn_global_load_lds((gptr_t)(uintptr_t)g, (lptr_t)(uintptr_t)l,
                                     16, 0, 0);
}

__device__ inline uint2 pack4bf(float a, float b, float c, float d) {
    union { __hip_bfloat16 h[4]; uint2 u; } o;
    o.h[0] = __float2bfloat16(a); o.h[1] = __float2bfloat16(b);
    o.h[2] = __float2bfloat16(c); o.h[3] = __float2bfloat16(d);
    return o.u;
}

__device__ inline float2 cmul(float2 a, float2 b) {
    return make_float2(a.x * b.x - a.y * b.y, a.x * b.y + a.y * b.x);
}
__device__ inline float2 cmad(float2 a, float2 b, float2 c) {
    // a*b + c
    return make_float2(a.x * b.x - a.y * b.y + c.x,
                       a.x * b.y + a.y * b.x + c.y);
}
__device__ inline float2 csq(float2 a) {
    return make_float2(a.x * a.x - a.y * a.y, 2.f * a.x * a.y);
}

// ---------- complex recurrence step: s = a*s + b*u ----------
__device__ inline void cstep(float& sr, float& si, float2 a, float2 bb,
                             uint32_t uw) {
    float ur = bf2f(uw & 0xffffu), ui = bf2f(uw >> 16);
    float tr = bb.x * ur - bb.y * ui;
    float ti = bb.x * ui + bb.y * ur;
    float nr = a.x * sr - a.y * si + tr;
    float ni = a.x * si + a.y * sr + ti;
    sr = nr; si = ni;
}

// ---------- fused prep + rmsnorm (R7-exact: block-per-token) ----------
__global__ __launch_bounds__(256) void prep_rms(
    const float* __restrict__ x, const float* __restrict__ w,
    const float* __restrict__ W_in, const float* __restrict__ W_out,
    const float* __restrict__ ap, const float* __restrict__ bp,
    const float* __restrict__ cp,
    __hip_bfloat16* __restrict__ xn,
    __hip_bfloat16* __restrict__ Win_bf, __hip_bfloat16* __restrict__ Wout_bf,
    float2* __restrict__ ac, float2* __restrict__ bc,
    float2* __restrict__ cc, float2* __restrict__ aL) {
    int bid = blockIdx.x;
    int tid = threadIdx.x;
    if (bid < M_TOK) {
        // ---- RMSNorm for token `bid` ----
        __shared__ float wsum[3];
        float4 v = make_float4(0.f, 0.f, 0.f, 0.f);
        if (tid < 192) v = ((const float4*)(x + (size_t)bid * DM))[tid];
        float ss = v.x * v.x + v.y * v.y + v.z * v.z + v.w * v.w;
        #pragma unroll
        for (int o = 1; o < 64; o <<= 1) ss += __shfl_xor(ss, o);
        if (tid < 192 && (tid & 63) == 0) wsum[tid >> 6] = ss;
        __syncthreads();
        if (tid < 192) {
            float tot = wsum[0] + wsum[1] + wsum[2];
            float scale = rsqrtf(tot * (1.f / DM) + 1e-6f);
            float4 wv = ((const float4*)w)[tid];
            ((uint2*)(xn + (size_t)bid * DM))[tid] =
                pack4bf(v.x * scale * wv.x, v.y * scale * wv.y,
                        v.z * scale * wv.z, v.w * scale * wv.w);
        }
        return;
    }
    const int N1 = NFEAT * DM / 4;   // float4 count
    const int N2 = DM * DM / 4;
    int i = (bid - M_TOK) * 256 + tid;
    if (i < N1) {
        float4 v = ((const float4*)W_in)[i];
        ((uint2*)Win_bf)[i] = pack4bf(v.x, v.y, v.z, v.w);
    } else if (i < N1 + N2) {
        int k = i - N1;
        float4 v = ((const float4*)W_out)[k];
        ((uint2*)Wout_bf)[k] = pack4bf(v.x, v.y, v.z, v.w);
    }
    if (i < DM * RR) {
        float ar = tanhf(ap[2 * i])     * 0.97f;
        float ai = tanhf(ap[2 * i + 1]) * 0.97f;
        ac[i] = make_float2(ar, ai);
        bc[i] = make_float2(tanhf(bp[2 * i]), tanhf(bp[2 * i + 1]));
        cc[i] = make_float2(tanhf(cp[2 * i]), tanhf(cp[2 * i + 1]));
        float xr = ar, xi = ai;   // a^64 via 6 squarings
        #pragma unroll
        for (int k = 0; k < 6; ++k) {
            float nr = xr * xr - xi * xi;
            float ni = 2.f * xr * xi;
            xr = nr; xi = ni;
        }
        aL[i] = make_float2(xr, xi);
    }
}

// ---------- gemm_in: R9/R13 config — measured optimum (45.9us) ----------
// Full family bracket: R0 single-buf=50.4; R8 dbuf-256thr=47.5; R9/R11/R13
// dbuf-512thr=45.0-46.1 (BEST; at the 2-barrier family's LDS-port ceiling:
// 34.5us ds_reads + 11.8us staging ~ 46.3); R10 128x256 1blk/CU=51.2;
// R12 BK=32=59.6 (barrier cadence); R14 fused-scan=73.4 (write amp + tail);
// R15 XCD swizzle=53.8 (FETCH 36.9->141MB: each XCD streamed ALL of W_in —
// default linear dispatch already optimal for this panel-sharing pattern).
// This is the final configuration. DO NOT swizzle blockIdx here.
__global__ __launch_bounds__(512, 4) void gemm_in(
    const __hip_bfloat16* __restrict__ A, const __hip_bfloat16* __restrict__ B,
    __hip_bfloat16* __restrict__ C, int K) {
    constexpr int BM = 128, BN = 128, BK = 64;
    constexpr int CPR = BK / 8;           // 8 chunks per row
    constexpr int ldc = NFEAT;
    __shared__ __attribute__((aligned(16))) __hip_bfloat16
        lds2[2][BM * BK + BN * BK];
    const int tid  = threadIdx.x;
    const int lane = tid & 63;
    const int wave = tid >> 6;            // 0..7
    const int quad = lane >> 4;
    const int l15  = lane & 15;
    const int wm = (wave >> 2) * 64;      // 2 wave-rows
    const int wn = (wave & 3) * 32;       // 4 wave-cols
    const int m0 = blockIdx.y * BM;
    const int n0 = blockIdx.x * BN;

    float4v acc[4][2] = {};

    auto stage = [&](int bi, int t) {
        __hip_bfloat16* sA = lds2[bi];
        __hip_bfloat16* sB = lds2[bi] + BM * BK;
        const int k0 = t * BK;
        #pragma unroll
        for (int it = 0; it < BM * CPR / 512; ++it) {   // 2
            int p = it * 512 + tid;
            int row = p >> 3;
            int cg = (p & 7) ^ (row & 7);
            async_ld16(A + (size_t)(m0 + row) * K + k0 + cg * 8, sA + p * 8);
        }
        #pragma unroll
        for (int it = 0; it < BN * CPR / 512; ++it) {   // 2
            int p = it * 512 + tid;
            int row = p >> 3;
            int cg = (p & 7) ^ (row & 7);
            async_ld16(B + (size_t)(n0 + row) * K + k0 + cg * 8, sB + p * 8);
        }
    };

    const int nt = K / BK;          // 12
    stage(0, 0);
    for (int t = 0; t < nt; ++t) {
        const int cur = t & 1;
        if (t + 1 < nt) {
            stage(cur ^ 1, t + 1);
            asm volatile("s_waitcnt vmcnt(4)" ::: "memory");
        } else {
            asm volatile("s_waitcnt vmcnt(0)" ::: "memory");
        }
        asm volatile("s_barrier" ::: "memory");
        const __hip_bfloat16* lA = lds2[cur];
        const __hip_bfloat16* lB = lds2[cur] + BM * BK;
        #pragma unroll
        for (int s = 0; s < BK / 32; ++s) {
            short8 af[4], bfr[2];
            #pragma unroll
            for (int i = 0; i < 4; ++i) {
                int r = wm + i * 16 + l15;
                int c = (s * 4 + quad) ^ (r & 7);
                af[i] = *(const short8*)(lA + r * BK + c * 8);
            }
            #pragma unroll
            for (int j = 0; j < 2; ++j) {
                int r = wn + j * 16 + l15;
                int c = (s * 4 + quad) ^ (r & 7);
                bfr[j] = *(const short8*)(lB + r * BK + c * 8);
            }
            #pragma unroll
            for (int i = 0; i < 4; ++i)
                #pragma unroll
                for (int j = 0; j < 2; ++j)
                    acc[i][j] = __builtin_amdgcn_mfma_f32_16x16x32_bf16(
                        af[i], bfr[j], acc[i][j], 0, 0, 0);
        }
        asm volatile("s_waitcnt lgkmcnt(0)" ::: "memory");
        asm volatile("s_barrier" ::: "memory");
    }
    // epilogue: C/D layout col = lane&15, row = quad*4 + reg (m89-verified)
    #pragma unroll
    for (int i = 0; i < 4; ++i)
        #pragma unroll
        for (int j = 0; j < 2; ++j)
            #pragma unroll
            for (int rg = 0; rg < 4; ++rg) {
                int row = m0 + wm + i * 16 + quad * 4 + rg;
                int col = n0 + wn + j * 16 + l15;
                C[(size_t)row * ldc + col] = __float2bfloat16(acc[i][j][rg]);
            }
}

// ---------- gemm_out v2: counted-vmcnt dbuf at 64x64 (R13, passing) -------
__global__ __launch_bounds__(256, 4) void gemm_out(
    const __hip_bfloat16* __restrict__ A, const __hip_bfloat16* __restrict__ B,
    float* __restrict__ C, int K) {
    constexpr int BM = 64, BN = 64, BK = 64;
    constexpr int CPR = BK / 8;           // 8
    constexpr int ldc = DM;
    __shared__ __attribute__((aligned(16))) __hip_bfloat16
        lds2[2][(BM + BN) * BK];
    const int tid  = threadIdx.x;
    const int lane = tid & 63;
    const int wave = tid >> 6;            // 0..3
    const int quad = lane >> 4;
    const int l15  = lane & 15;
    const int wm = (wave >> 1) * 32;      // 2 wave-rows
    const int wn = (wave & 1) * 32;       // 2 wave-cols
    const int m0 = blockIdx.y * BM;
    const int n0 = blockIdx.x * BN;

    float4v acc[2][2] = {};

    auto stage = [&](int bi, int t) {
        __hip_bfloat16* sA = lds2[bi];
        __hip_bfloat16* sB = lds2[bi] + BM * BK;
        const int k0 = t * BK;
        #pragma unroll
        for (int it = 0; it < BM * CPR / 256; ++it) {   // 2
            int p = it * 256 + tid;
            int row = p >> 3;
            int cg = (p & 7) ^ (row & 7);
            async_ld16(A + (size_t)(m0 + row) * K + k0 + cg * 8, sA + p * 8);
        }
        #pragma unroll
        for (int it = 0; it < BN * CPR / 256; ++it) {   // 2
            int p = it * 256 + tid;
            int row = p >> 3;
            int cg = (p & 7) ^ (row & 7);
            async_ld16(B + (size_t)(n0 + row) * K + k0 + cg * 8, sB + p * 8);
        }
    };

    const int nt = K / BK;          // 12
    stage(0, 0);
    for (int t = 0; t < nt; ++t) {
        const int cur = t & 1;
        if (t + 1 < nt) {
            stage(cur ^ 1, t + 1);
            asm volatile("s_waitcnt vmcnt(4)" ::: "memory");
        } else {
            asm volatile("s_waitcnt vmcnt(0)" ::: "memory");
        }
        asm volatile("s_barrier" ::: "memory");
        const __hip_bfloat16* lA = lds2[cur];
        const __hip_bfloat16* lB = lds2[cur] + BM * BK;
        #pragma unroll
        for (int s = 0; s < BK / 32; ++s) {
            short8 af[2], bfr[2];
            #pragma unroll
            for (int i = 0; i < 2; ++i) {
                int r = wm + i * 16 + l15;
                int c = (s * 4 + quad) ^ (r & 7);
                af[i] = *(const short8*)(lA + r * BK + c * 8);
            }
            #pragma unroll
            for (int j = 0; j < 2; ++j) {
                int r = wn + j * 16 + l15;
                int c = (s * 4 + quad) ^ (r & 7);
                bfr[j] = *(const short8*)(lB + r * BK + c * 8);
            }
            #pragma unroll
            for (int i = 0; i < 2; ++i)
                #pragma unroll
                for (int j = 0; j < 2; ++j)
                    acc[i][j] = __builtin_amdgcn_mfma_f32_16x16x32_bf16(
                        af[i], bfr[j], acc[i][j], 0, 0, 0);
        }
        asm volatile("s_waitcnt lgkmcnt(0)" ::: "memory");
        asm volatile("s_barrier" ::: "memory");
    }
    // epilogue: C/D layout col = lane&15, row = quad*4 + reg (m89-verified)
    #pragma unroll
    for (int i = 0; i < 2; ++i)
        #pragma unroll
        for (int j = 0; j < 2; ++j)
            #pragma unroll
            for (int rg = 0; rg < 4; ++rg) {
                int row = m0 + wm + i * 16 + quad * 4 + rg;
                int col = n0 + wn + j * 16 + l15;
                C[(size_t)row * ldc + col] = acc[i][j][rg];
            }
}

// ---------- scan_local2: standalone two-level chunk scan (R4, passing) ----
__global__ __launch_bounds__(256) void scan_local2(
    const uint4* __restrict__ u4,              // [token*768 + d] (4 ranks)
    const float2* __restrict__ ac, const float2* __restrict__ bc,
    const float2* __restrict__ cc,
    __hip_bfloat16* __restrict__ y_local,      // [M_TOK][DM] bf16
    float2* __restrict__ chunkEnd) {           // [NCHUNK][NCH]
    __shared__ float2 se[1024];                // 256 threads x 4 ranks
    const int tid   = threadIdx.x;
    const int d_loc = tid & 31;
    const int s8    = tid >> 5;
    const int bd    = blockIdx.x;              // 0..47
    const int b     = bd >= 24;
    const int dg    = bd - b * 24;
    const int d_g   = dg * 32 + d_loc;
    const int cb    = d_g * RR;
    const int j     = blockIdx.y;

    float2 a0 = ac[cb], a1 = ac[cb + 1], a2 = ac[cb + 2], a3 = ac[cb + 3];
    float2 b0 = bc[cb], b1 = bc[cb + 1], b2 = bc[cb + 2], b3 = bc[cb + 3];
    float2 c0 = cc[cb], c1 = cc[cb + 1], c2 = cc[cb + 2], c3 = cc[cb + 3];

    const int token0 = b * TT + j * CHUNK + s8 * 8;
    const size_t base = (size_t)token0 * DM + d_g;   // uint4 stride DM/token

    // Phase A: issue all 8 loads, then 8-token sub-scan (zero init)
    uint4 uw[8];
    #pragma unroll
    for (int i = 0; i < 8; ++i) uw[i] = u4[base + (size_t)i * DM];
    float s0r = 0, s0i = 0, s1r = 0, s1i = 0;
    float s2r = 0, s2i = 0, s3r = 0, s3i = 0;
    float yloc[8];
    #pragma unroll
    for (int i = 0; i < 8; ++i) {
        cstep(s0r, s0i, a0, b0, uw[i].x);
        cstep(s1r, s1i, a1, b1, uw[i].y);
        cstep(s2r, s2i, a2, b2, uw[i].z);
        cstep(s3r, s3i, a3, b3, uw[i].w);
        yloc[i] = c0.x * s0r - c0.y * s0i + c1.x * s1r - c1.y * s1i
                + c2.x * s2r - c2.y * s2i + c3.x * s3r - c3.y * s3i;
    }
    se[tid * 4]     = make_float2(s0r, s0i);
    se[tid * 4 + 1] = make_float2(s1r, s1i);
    se[tid * 4 + 2] = make_float2(s2r, s2i);
    se[tid * 4 + 3] = make_float2(s3r, s3i);
    __syncthreads();

    // Phase B: fold preceding sub-ends with aE = a^8
    float2 aE0 = csq(csq(csq(a0))), aE1 = csq(csq(csq(a1)));
    float2 aE2 = csq(csq(csq(a2))), aE3 = csq(csq(csq(a3)));
    float2 C0 = make_float2(0, 0), C1 = C0, C2 = C0, C3 = C0;
    for (int k = 0; k < s8; ++k) {
        int kb = (k * 32 + d_loc) * 4;
        C0 = cmad(C0, aE0, se[kb]);
        C1 = cmad(C1, aE1, se[kb + 1]);
        C2 = cmad(C2, aE2, se[kb + 2]);
        C3 = cmad(C3, aE3, se[kb + 3]);
    }
    // chunkEnd from slice 7: end = C*aE + own sub-end (still in regs)
    if (s8 == 7) {
        size_t eb = (size_t)j * NCH + b * (DM * RR) + cb;
        chunkEnd[eb]     = cmad(C0, aE0, make_float2(s0r, s0i));
        chunkEnd[eb + 1] = cmad(C1, aE1, make_float2(s1r, s1i));
        chunkEnd[eb + 2] = cmad(C2, aE2, make_float2(s2r, s2i));
        chunkEnd[eb + 3] = cmad(C3, aE3, make_float2(s3r, s3i));
    }
    // correction: y_i += Re(c * a^(i+1) * C), then store bf16
    float2 q0 = cmul(cmul(c0, C0), a0);
    float2 q1 = cmul(cmul(c1, C1), a1);
    float2 q2 = cmul(cmul(c2, C2), a2);
    float2 q3 = cmul(cmul(c3, C3), a3);
    #pragma unroll
    for (int i = 0; i < 8; ++i) {
        float yv = yloc[i] + q0.x + q1.x + q2.x + q3.x;
        y_local[base + (size_t)i * DM] = __float2bfloat16(yv);
        q0 = cmul(q0, a0); q1 = cmul(q1, a1);
        q2 = cmul(q2, a2); q3 = cmul(q3, a3);
    }
}

// ---------- carry_scan: per-channel sequential fold, IN PLACE (R7) --------
__global__ __launch_bounds__(256) void carry_scan(
    float2* __restrict__ chunkEnd,             // [NCHUNK][NCH], in/out
    const float2* __restrict__ aLp) {          // [DM*RR] = a^64
    int ch = blockIdx.x * 256 + threadIdx.x;   // 0..NCH-1 = b*(DM*RR)+d*RR+r
    int dr = (ch >= DM * RR) ? ch - DM * RR : ch;
    float2 aL = aLp[dr];
    float2 K = make_float2(0.f, 0.f);
    for (int j = 0; j < NCHUNK; ++j) {
        size_t idx = (size_t)j * NCH + ch;
        float2 e = chunkEnd[idx];
        chunkEnd[idx] = K;
        K = cmad(K, aL, e);
    }
}

// ---------- scan_fix: foldless carry correction, IN PLACE (R7) ------------
__global__ __launch_bounds__(256) void scan_fix(
    __hip_bfloat16* __restrict__ y_local,      // in/out [M_TOK][DM]
    const float2* __restrict__ ac, const float2* __restrict__ cc,
    const float2* __restrict__ carry) {        // [NCHUNK][NCH] (=chunkEnd)
    const int tid   = threadIdx.x;
    const int d_loc = tid & 31;
    const int s8    = tid >> 5;
    const int bd    = blockIdx.x;              // 0..47
    const int b     = bd >= 24;
    const int dg    = bd - b * 24;
    const int d_g   = dg * 32 + d_loc;
    const int cb    = d_g * RR;
    const int j     = blockIdx.y;
    const size_t kb = (size_t)j * NCH + b * (DM * RR) + cb;

    float2 a0 = ac[cb], a1 = ac[cb + 1], a2 = ac[cb + 2], a3 = ac[cb + 3];
    float2 c0 = cc[cb], c1 = cc[cb + 1], c2 = cc[cb + 2], c3 = cc[cb + 3];
    float2 K0 = carry[kb],     K1 = carry[kb + 1];
    float2 K2 = carry[kb + 2], K3 = carry[kb + 3];

    // q = c * K * a^(8*s8 + 1)
    float2 aE0 = csq(csq(csq(a0))), aE1 = csq(csq(csq(a1)));
    float2 aE2 = csq(csq(csq(a2))), aE3 = csq(csq(csq(a3)));
    float2 q0 = cmul(cmul(c0, K0), a0);
    float2 q1 = cmul(cmul(c1, K1), a1);
    float2 q2 = cmul(cmul(c2, K2), a2);
    float2 q3 = cmul(cmul(c3, K3), a3);
    for (int t = 0; t < s8; ++t) {
        q0 = cmul(q0, aE0); q1 = cmul(q1, aE1);
        q2 = cmul(q2, aE2); q3 = cmul(q3, aE3);
    }
    const int token0 = b * TT + j * CHUNK + s8 * 8;
    const size_t base = (size_t)token0 * DM + d_g;
    #pragma unroll
    for (int i = 0; i < 8; ++i) {
        size_t idx = base + (size_t)i * DM;
        float yv = bf2f(((const uint16_t*)y_local)[idx])
                 + q0.x + q1.x + q2.x + q3.x;
        y_local[idx] = __float2bfloat16(yv);
        q0 = cmul(q0, a0); q1 = cmul(q1, a1);
        q2 = cmul(q2, a2); q3 = cmul(q3, a3);
    }
}

// ---------- launch ----------
extern "C" void kernel_launch(void* const* d_in, const int* in_sizes, int n_in,
                              void* d_out, int out_size, void* d_ws,
                              size_t ws_size, hipStream_t stream) {
    const float* x      = (const float*)d_in[0];
    const float* norm_w = (const float*)d_in[1];
    const float* W_in   = (const float*)d_in[2];
    const float* W_out  = (const float*)d_in[3];
    const float* a_p    = (const float*)d_in[4];
    const float* b_p    = (const float*)d_in[5];
    const float* c_p    = (const float*)d_in[6];
    float* out = (float*)d_out;

    char* ws = (char*)d_ws;
    size_t off = 0;
    auto alloc = [&](size_t bytes) {
        void* p = ws + off;
        off += (bytes + 255) & ~(size_t)255;
        return p;
    };
    __hip_bfloat16* Win_bf  = (__hip_bfloat16*)alloc((size_t)NFEAT * DM * 2);
    __hip_bfloat16* Wout_bf = (__hip_bfloat16*)alloc((size_t)DM * DM * 2);
    __hip_bfloat16* xn      = (__hip_bfloat16*)alloc((size_t)M_TOK * DM * 2);
    __hip_bfloat16* u       = (__hip_bfloat16*)alloc((size_t)M_TOK * NFEAT * 2);
    __hip_bfloat16* y_local = (__hip_bfloat16*)alloc((size_t)M_TOK * DM * 2);
    float2* ac = (float2*)alloc((size_t)DM * RR * 8);
    float2* bc = (float2*)alloc((size_t)DM * RR * 8);
    float2* cc = (float2*)alloc((size_t)DM * RR * 8);
    float2* aL = (float2*)alloc((size_t)DM * RR * 8);
    float2* chunkEnd = (float2*)alloc((size_t)NCHUNK * NCH * 8);

    // 1. fused prep (weight casts + coeffs) + RMSNorm
    {
        int cast_blocks = ((NFEAT * DM + DM * DM) / 4 + 255) / 256;
        prep_rms<<<M_TOK + cast_blocks, 256, 0, stream>>>(
            x, norm_w, W_in, W_out, a_p, b_p, c_p,
            xn, Win_bf, Wout_bf, ac, bc, cc, aL);
    }
    // 2. in_proj GEMM: u = xn @ W_in^T  (R9 config: 128^2, 512thr, vmcnt)
    gemm_in<<<dim3(NFEAT / 128, M_TOK / 128), 512, 0, stream>>>(
        xn, Win_bf, u, DM);
    // 3. two-level chunk scan: u -> y_local + chunkEnd
    scan_local2<<<dim3(48, NCHUNK), 256, 0, stream>>>(
        (const uint4*)u, ac, bc, cc, y_local, chunkEnd);
    // 4. per-channel carry fold (in place: chunkEnd -> carry-entering-chunk)
    carry_scan<<<NCH / 256, 256, 0, stream>>>(chunkEnd, aL);
    // 5. foldless correction, in place on y_local
    scan_fix<<<dim3(48, NCHUNK), 256, 0, stream>>>(
        y_local, ac, cc, chunkEnd);
    // 6. out_proj GEMM (counted-vmcnt dbuf, 64^2, BK=64)
    gemm_out<<<dim3(DM / 64, M_TOK / 64), 256, 0, stream>>>(
        y_local, Wout_bf, out, DM);
}